// Round 8
// baseline (492.125 us; speedup 1.0000x reference)
//
#include <hip/hip_runtime.h>

// SimpleMemoryNetwork: T=64,B=128,H=256,NI=2,NO=10, lambda=.95, eta=.5, sample=32, decision=8
// R8 = R6 (256 blocks = 64 batch-groups x 4 col-slices, 512 thr, 1 blk/CU) with:
//  * lgkm-only barriers (loads/stores stay in flight); ONE full __syncthreads per step
//    (in B after loads consumed; dead steps: post-gather) to order resent->signal chains.
//  * Re-sentinels moved to same-thread-same-address as the future republish
//    (state: in A-combine, slot (t+2)&3; c: in dots, slot (mc+2)&3; mu: in fin, as before).
//  * B weights (W_ro/W_ao) preloaded into registers right after A -> stream overlaps
//    state gather + mu poll + o finish.
//  * Dots split: s<=t-2 pre-fin (covers state RT), s=t-1 post-fin.
// o dead for t in 33..55: those steps run only the a/r recurrence + state exchange.

typedef unsigned long long u64;

#define HH 256
#define NSTEPS 64

// ws layout (float offsets)
#define OFF_ST 0u          // st64[4][128][256] u64
#define OFF_C  262144u     // c_parts[4][33][128][4] f32
#define OFF_MU 329728u     // mu64[4][4][64][32] u64
#define WS_FLOATS 395264u  // ~1.58 MB

#define SENT_STATE   0xBF800000BF800000ull
#define SENT_C       0xBF800000u
#define SENT_MU      0x7FC00000u
#define SENT_MU_PAIR 0x7FC000007FC00000ull

#define AGENT __HIP_MEMORY_SCOPE_AGENT
#define RLX   __ATOMIC_RELAXED

#define BAR_LGKM() asm volatile("s_waitcnt lgkmcnt(0)\ns_barrier" ::: "memory")

__device__ __forceinline__ u64 ld64(const u64* p){ return __hip_atomic_load(p,RLX,AGENT); }
__device__ __forceinline__ void st64s(u64* p,u64 v){ __hip_atomic_store(p,v,RLX,AGENT); }
__device__ __forceinline__ float ld32f(const float* p){ return __hip_atomic_load(p,RLX,AGENT); }
__device__ __forceinline__ void st32f(float* p,float v){ __hip_atomic_store(p,v,RLX,AGENT); }
__device__ __forceinline__ u64 pack2(float lo,float hi){
  return (u64)__float_as_uint(lo) | ((u64)__float_as_uint(hi)<<32);
}

__global__ __launch_bounds__(256) void smn_init(float* __restrict__ ws,
                                                float* __restrict__ out){
  unsigned i = blockIdx.x*256u + threadIdx.x, st = gridDim.x*256u;
  u64* stp=(u64*)(ws+OFF_ST); float* cp=ws+OFF_C; u64* mp=(u64*)(ws+OFF_MU);
  for (unsigned k=i;k<131072u;k+=st) st64s(&stp[k],SENT_STATE);
  for (unsigned k=i;k<67584u;k+=st)  st32f(&cp[k],__uint_as_float(SENT_C));
  for (unsigned k=i;k<32768u;k+=st)  st64s(&mp[k],SENT_MU_PAIR);
  for (unsigned k=i;k<10240u;k+=st)  out[k]=0.f;
}

__global__ __launch_bounds__(512,2) void smn_main(
    const float* __restrict__ x_in, const float* __restrict__ W_sr,
    const float* __restrict__ W_ma, const float* __restrict__ W_ro,
    const float* __restrict__ W_ao, const float* __restrict__ W_ar,
    const float* __restrict__ W_ra, const float* __restrict__ W_a,
    const float* __restrict__ W_y,  const float* __restrict__ gvec,
    const float* __restrict__ bvec, float* __restrict__ out,
    float* __restrict__ ws)
{
  __shared__ __align__(16) float aF[2][HH], rF[2][HH];   // full state(t)
  __shared__ __align__(16) float P[2][32][2][64];        // k-split matvec partials
  __shared__ __align__(16) float r_hist[33][2][64];
  __shared__ __align__(16) float o_hist[33][2][64];
  __shared__ float opre[2][64];
  __shared__ float c_l[33][2];
  __shared__ float mu_l[64];
  __shared__ float muG[16][32][2];
  __shared__ float lam_pow[64];
  __shared__ float x_l[2][5];
  __shared__ float lds_pad[8192];     // force 1 block/CU

  const int tid = threadIdx.x;
  const int bid = blockIdx.x;
  const int grp = bid >> 2, jsl = bid & 3;
  const int b0 = grp * 2, c0 = jsl * 64;
  const int q = tid & 15, ks = tid >> 4;       // matvec map

  u64*   st64    = (u64*)(ws + OFF_ST);
  float* c_parts = ws + OFF_C;
  u64*   mu64    = (u64*)(ws + OFF_MU);

  if (out == nullptr) lds_pad[tid] = 1.f;      // never true; keeps pad allocated

  const int cc2 = c0 + (tid & 63);
  const float gv  = gvec[cc2], bv = bvec[cc2];
  const float wma0=W_ma[cc2], wma1=W_ma[HH+cc2], wma2=W_ma[2*HH+cc2];
  const float wsr0=W_sr[cc2], wsr1=W_sr[HH+cc2];
  if (tid < 64) lam_pow[tid] = powf(0.95f,(float)tid);
  if (tid < 10) x_l[tid/5][tid%5] = x_in[(b0 + tid/5)*5 + tid%5];   // x(0)
  __syncthreads();

  for (int t = 0; t <= NSTEPS; ++t) {
    const bool live = (t <= 32 || t >= 56);
    const int mc = (t <= 32) ? t : t - 23;

    // ================= A: state(t) own slice =================
    if (t < NSTEPS) {
      if (t == 0) {
        if (tid < 128) {
          int b = tid>>6, c = tid&63;
          float va = fmaxf(x_l[b][2]*wma0 + x_l[b][3]*wma1 + x_l[b][4]*wma2, 0.f);
          float vr = fmaxf(x_l[b][0]*wsr0 + x_l[b][1]*wsr1, 0.f);
          aF[b][c0+c]=va; rF[b][c0+c]=vr; r_hist[0][b][c]=vr;
          st64s(&st64[(unsigned)(2*32768) + (unsigned)((b0+b)*HH + cc2)], SENT_STATE);
          st64s(&st64[(unsigned)((b0+b)*HH + cc2)], pack2(va,vr));
        }
        BAR_LGKM();
      } else {
        const int kb = ks*8;
        float sa0[8],sa1[8],sr0[8],sr1[8];
        *(float4*)&sa0[0]=*(const float4*)&aF[0][kb]; *(float4*)&sa0[4]=*(const float4*)&aF[0][kb+4];
        *(float4*)&sa1[0]=*(const float4*)&aF[1][kb]; *(float4*)&sa1[4]=*(const float4*)&aF[1][kb+4];
        *(float4*)&sr0[0]=*(const float4*)&rF[0][kb]; *(float4*)&sr0[4]=*(const float4*)&rF[0][kb+4];
        *(float4*)&sr1[0]=*(const float4*)&rF[1][kb]; *(float4*)&sr1[4]=*(const float4*)&rF[1][kb+4];
        float aA[2][4]={{0.f,0.f,0.f,0.f},{0.f,0.f,0.f,0.f}};
        float aR[2][4]={{0.f,0.f,0.f,0.f},{0.f,0.f,0.f,0.f}};
        #pragma unroll
        for (int kk=0; kk<8; ++kk) {
          const int k = kb + kk;
          const float4 wa = *(const float4*)&W_a [k*HH + c0 + q*4];
          const float4 wr = *(const float4*)&W_ra[k*HH + c0 + q*4];
          const float4 wn = *(const float4*)&W_ar[k*HH + c0 + q*4];
          #pragma unroll
          for (int jj=0;jj<4;++jj){
            const float waj=(&wa.x)[jj], wrj=(&wr.x)[jj], wnj=(&wn.x)[jj];
            aA[0][jj] += sa0[kk]*waj + sr0[kk]*wrj;
            aA[1][jj] += sa1[kk]*waj + sr1[kk]*wrj;
            aR[0][jj] += sa0[kk]*wnj;
            aR[1][jj] += sa1[kk]*wnj;
          }
        }
        *(float4*)&P[0][ks][0][q*4] = make_float4(aA[0][0],aA[0][1],aA[0][2],aA[0][3]);
        *(float4*)&P[0][ks][1][q*4] = make_float4(aA[1][0],aA[1][1],aA[1][2],aA[1][3]);
        *(float4*)&P[1][ks][0][q*4] = make_float4(aR[0][0],aR[0][1],aR[0][2],aR[0][3]);
        *(float4*)&P[1][ks][1][q*4] = make_float4(aR[1][0],aR[1][1],aR[1][2],aR[1][3]);
        BAR_LGKM();
        if (tid < 128) {
          int b=tid>>6, c=tid&63;
          float sa=0.f, sr=0.f;
          #pragma unroll
          for (int e=0;e<32;++e){ sa+=P[0][e][b][c]; sr+=P[1][e][b][c]; }
          float va = fmaxf(sa + x_l[b][2]*wma0 + x_l[b][3]*wma1 + x_l[b][4]*wma2, 0.f);
          float vr = fmaxf(sr + x_l[b][0]*wsr0 + x_l[b][1]*wsr1, 0.f);
          if (t<=32) r_hist[t][b][c]=vr;
          // resent slot (t+2)&3 (occupant t-2: peers' consumption proven by my gather(t-1);
          // same thread+address as my publish at t+2 -> per-location order, no drain needed
          // for self; cross-observer ordering via the per-step full sync below)
          st64s(&st64[(unsigned)(((t+2)&3)*32768) + (unsigned)((b0+b)*HH + cc2)], SENT_STATE);
          st64s(&st64[(unsigned)((t&3)*32768) + (unsigned)((b0+b)*HH + cc2)], pack2(va,vr));
          aF[b][c0+c]=va; rF[b][c0+c]=vr;
        }
        BAR_LGKM();
      }
      if (t+1 < NSTEPS && tid < 10)
        x_l[tid/5][tid%5] = x_in[((t+1)*128 + b0 + tid/5)*5 + tid%5];
    }

    // ====== B-weight preload (issued early; consumed after fin) ======
    float4 woR[8], wqR[8];
    if (t < NSTEPS && live) {
      const int kb = ks*8;
      #pragma unroll
      for (int kk=0;kk<8;++kk){
        woR[kk] = *(const float4*)&W_ro[(kb+kk)*HH + c0 + q*4];
        wqR[kk] = *(const float4*)&W_ao[(kb+kk)*HH + c0 + q*4];
      }
    }

    // ======== dots (s<=t-2) publish ∥ state(t) gather ========
    if (t < NSTEPS) {
      const int smax_old = ((t-2) < 32) ? (t-2) : 32;
      if (tid < 128) {
        if (live && smax_old >= 0) {
          const int l8 = tid & 7;
          for (int pp = tid>>3; pp < (smax_old+1)*2; pp += 16) {
            const int s = pp>>1, b2 = pp&1;
            float acc=0.f;
            #pragma unroll
            for (int i2=0;i2<8;++i2){ int c=l8*8+i2; acc += rF[b2][c0+c]*o_hist[s][b2][c]; }
            acc+=__shfl_xor(acc,1); acc+=__shfl_xor(acc,2); acc+=__shfl_xor(acc,4);
            if (l8==0) {
              st32f(&c_parts[(unsigned)(((((mc+2)&3)*33+s)*128 + b0+b2)*4 + jsl)],
                    __uint_as_float(SENT_C));                       // resent (occupant mc-2)
              st32f(&c_parts[(unsigned)((((mc&3)*33+s)*128 + b0+b2)*4 + jsl)], acc);
            }
          }
        }
      } else {
        const int w = tid - 128;                 // 384 threads: 3 peers x 128 words
        const int pi = w >> 7, w2 = w & 127, b = w2>>6, c64 = w2&63;
        const int jp = (jsl + 1 + pi) & 3;
        const u64* ptr = &st64[(unsigned)((t&3)*32768) + (unsigned)((b0+b)*HH + jp*64 + c64)];
        u64 v;
        for (;;){ v = ld64(ptr); if (v != SENT_STATE) break; }
        aF[b][jp*64+c64] = __uint_as_float((unsigned)v);
        rF[b][jp*64+c64] = __uint_as_float((unsigned)(v>>32));
      }
      if (live) { BAR_LGKM(); } else { __syncthreads(); }  // dead steps: per-step full drain
    }

    // ================= fin: finish o(t-1) (late mu poll) =================
    const int tp = t - 1;
    if (t >= 1 && (tp <= 32 || tp >= 56)) {
      const int m = (tp <= 32) ? tp : tp - 23;
      {
        const int p = tid & 31, ch = tid >> 5;
        const u64* base = &mu64[(unsigned)(((m&3)*4 + jsl)*64)*32u];
        u64 vals[4]; unsigned rm = 0;
        const u64* ptrs[4];
        #pragma unroll
        for (int gg=0; gg<4; ++gg) ptrs[gg] = &base[(unsigned)((ch*4+gg)*32 + p)];
        while (rm != 0xFu) {
          #pragma unroll
          for (int gg=0; gg<4; ++gg) if (!(rm & (1u<<gg))) {
            u64 v = ld64(ptrs[gg]);
            if ((unsigned)v != SENT_MU && (unsigned)(v>>32) != SENT_MU) { vals[gg]=v; rm |= 1u<<gg; }
          }
        }
        float s0=0.f, s1=0.f;
        #pragma unroll
        for (int gg=0; gg<4; ++gg) { s0 += __uint_as_float((unsigned)vals[gg]);
                                     s1 += __uint_as_float((unsigned)(vals[gg]>>32)); }
        muG[ch][p][0]=s0; muG[ch][p][1]=s1;
      }
      BAR_LGKM();
      if (tid < 32) {   // reduce + resent mu slot (m+3)&3 (same thread+address as republish)
        float s0=0.f,s1=0.f;
        #pragma unroll
        for (int ch2=0;ch2<16;++ch2){ s0+=muG[ch2][tid][0]; s1+=muG[ch2][tid][1]; }
        mu_l[2*tid]=s0*(1.f/128.f); mu_l[2*tid+1]=s1*(1.f/128.f);
        st64s(&mu64[(unsigned)((((m+3)&3)*4 + jsl)*64 + grp)*32u + (unsigned)tid], SENT_MU_PAIR);
      }
      BAR_LGKM();
      if (tid < 128) {
        int b=tid>>6, c=tid&63;
        float o = fmaxf(gv*(opre[b][c]-mu_l[c]) + bv, 0.f);
        opre[b][c]=o;
        if (tp<=32) o_hist[tp][b][c]=o;
      }
      BAR_LGKM();
      if (tp >= 56 && tid < 320) {
        int ow=tid>>4, l16=tid&15, b=ow/10, n=ow%10;
        float acc=0.f;
        #pragma unroll
        for (int i2=0;i2<4;++i2){ int c=l16*4+i2; acc += opre[b][c]*W_y[(c0+c)*10+n]; }
        acc+=__shfl_xor(acc,1); acc+=__shfl_xor(acc,2);
        acc+=__shfl_xor(acc,4); acc+=__shfl_xor(acc,8);
        if (l16==0) atomicAdd(&out[(tp-56)*1280 + (b0+b)*10 + n], acc);
      }
    }
    if (t == NSTEPS) break;

    // ================= post-fin dot s = t-1 =================
    if (live && t >= 1 && t <= 33) {
      if (tid < 16) {
        const int s = t-1, b2 = tid>>3, l8 = tid&7;
        float acc=0.f;
        #pragma unroll
        for (int i2=0;i2<8;++i2){ int c=l8*8+i2; acc += rF[b2][c0+c]*o_hist[s][b2][c]; }
        acc+=__shfl_xor(acc,1); acc+=__shfl_xor(acc,2); acc+=__shfl_xor(acc,4);
        if (l8==0) {
          st32f(&c_parts[(unsigned)(((((mc+2)&3)*33+s)*128 + b0+b2)*4 + jsl)],
                __uint_as_float(SENT_C));
          st32f(&c_parts[(unsigned)((((mc&3)*33+s)*128 + b0+b2)*4 + jsl)], acc);
        }
      }
    }

    // ================= B: o_pre (regs) + c gather + apply + mu publish =================
    if (live) {
      const int kb = ks*8;
      float sa0[8],sa1[8],sr0[8],sr1[8];
      *(float4*)&sa0[0]=*(const float4*)&aF[0][kb]; *(float4*)&sa0[4]=*(const float4*)&aF[0][kb+4];
      *(float4*)&sa1[0]=*(const float4*)&aF[1][kb]; *(float4*)&sa1[4]=*(const float4*)&aF[1][kb+4];
      *(float4*)&sr0[0]=*(const float4*)&rF[0][kb]; *(float4*)&sr0[4]=*(const float4*)&rF[0][kb+4];
      *(float4*)&sr1[0]=*(const float4*)&rF[1][kb]; *(float4*)&sr1[4]=*(const float4*)&rF[1][kb+4];
      float aO[2][4]={{0.f,0.f,0.f,0.f},{0.f,0.f,0.f,0.f}};
      #pragma unroll
      for (int kk=0;kk<8;++kk){
        #pragma unroll
        for (int jj=0;jj<4;++jj){
          const float woj=(&woR[kk].x)[jj], wqj=(&wqR[kk].x)[jj];
          aO[0][jj] += sr0[kk]*woj + sa0[kk]*wqj;
          aO[1][jj] += sr1[kk]*woj + sa1[kk]*wqj;
        }
      }
      *(float4*)&P[0][ks][0][q*4] = make_float4(aO[0][0],aO[0][1],aO[0][2],aO[0][3]);
      *(float4*)&P[0][ks][1][q*4] = make_float4(aO[1][0],aO[1][1],aO[1][2],aO[1][3]);
      // c gather: 4 parts per (s,b)
      const int smax = (t-1 < 32) ? (t-1) : 32;
      if (smax >= 0 && tid < (smax+1)*8) {
        const int s=tid>>3, b2=(tid>>2)&1, jj2=tid&3;
        const float* ptr=&c_parts[(unsigned)((((mc&3)*33+s)*128 + b0+b2)*4 + jj2)];
        float v;
        for(;;){ v=ld32f(ptr); if (__float_as_uint(v)!=SENT_C) break; }
        v+=__shfl_xor(v,1); v+=__shfl_xor(v,2);
        if (jj2==0) c_l[s][b2]=v;
      }
      __syncthreads();   // THE per-step full drain (orders resent stores before next signals)
      if (tid < 128) {
        int b=tid>>6, c=tid&63;
        float s=0.f;
        #pragma unroll
        for (int e=0;e<32;++e) s+=P[0][e][b][c];
        for (int s2=0;s2<=smax;++s2)
          s += lam_pow[t-1-s2]*0.5f*c_l[s2][b]*r_hist[s2][b][c];
        opre[b][c]=s;
      }
      BAR_LGKM();
      if (tid < 32) {
        float plo=opre[0][2*tid]+opre[1][2*tid];
        float phi=opre[0][2*tid+1]+opre[1][2*tid+1];
        st64s(&mu64[(unsigned)(((mc&3)*4 + jsl)*64 + grp)*32u + (unsigned)tid], pack2(plo,phi));
      }
    }
  }
}

extern "C" void kernel_launch(void* const* d_in, const int* in_sizes, int n_in,
                              void* d_out, int out_size, void* d_ws, size_t ws_size,
                              hipStream_t stream) {
  if (ws_size < (size_t)WS_FLOATS * 4) return;   // ~1.6 MB scratch
  const float* x_in = (const float*)d_in[0];
  const float* W_sr = (const float*)d_in[1];
  const float* W_ma = (const float*)d_in[2];
  const float* W_ro = (const float*)d_in[3];
  const float* W_ao = (const float*)d_in[4];
  const float* W_ar = (const float*)d_in[5];
  const float* W_ra = (const float*)d_in[6];
  const float* W_a  = (const float*)d_in[7];
  const float* W_y  = (const float*)d_in[8];
  const float* g    = (const float*)d_in[9];
  const float* b    = (const float*)d_in[10];
  float* out = (float*)d_out;
  float* ws  = (float*)d_ws;

  hipLaunchKernelGGL(smn_init, dim3(256), dim3(256), 0, stream, ws, out);
  hipLaunchKernelGGL(smn_main, dim3(256), dim3(512), 0, stream,
                     x_in, W_sr, W_ma, W_ro, W_ao, W_ar, W_ra, W_a, W_y, g, b,
                     out, ws);
}

// Round 9
// 379.890 us; speedup vs baseline: 1.2954x; 1.2954x over previous
//
#include <hip/hip_runtime.h>
#include <hip/hip_fp16.h>

// SimpleMemoryNetwork: T=64,B=128,H=256,NI=2,NO=10, lambda=.95, eta=.5, sample=32, decision=8
// R9 = R6 (best: 367us; 256 blocks = 64 batch-groups x 4 col-slices, 512 thr, 1 blk/CU,
// barrier-free sentinel dataflow, late mu poll) + ONE change:
//   W_ro/W_ao converted once to fp16 (init kernel) and held LDS-RESIDENT per block
//   (65.5 KB for this block's 64-col slice). Live-step L2 stream drops 327->196 KB
//   and the B matvec loses its L2 latency chain. No other changes vs R6.
// fp16 is o-path only (no feedback into a/r recurrence; recurrence weights stay fp32).

typedef unsigned long long u64;

#define HH 256
#define NSTEPS 64

// ws layout (float offsets)
#define OFF_ST 0u          // st64[4][128][256] u64
#define OFF_C  262144u     // c_parts[4][33][128][4] f32
#define OFF_MU 329728u     // mu64[4][4][64][32] u64
#define OFF_H  395264u     // half weights: hw_ro[4][256][64], hw_ao[4][256][64]
#define WS_FLOATS 460800u  // ~1.84 MB

#define SENT_STATE   0xBF800000BF800000ull
#define SENT_C       0xBF800000u
#define SENT_MU      0x7FC00000u
#define SENT_MU_PAIR 0x7FC000007FC00000ull

#define AGENT __HIP_MEMORY_SCOPE_AGENT
#define RLX   __ATOMIC_RELAXED

__device__ __forceinline__ u64 ld64(const u64* p){ return __hip_atomic_load(p,RLX,AGENT); }
__device__ __forceinline__ void st64s(u64* p,u64 v){ __hip_atomic_store(p,v,RLX,AGENT); }
__device__ __forceinline__ float ld32f(const float* p){ return __hip_atomic_load(p,RLX,AGENT); }
__device__ __forceinline__ void st32f(float* p,float v){ __hip_atomic_store(p,v,RLX,AGENT); }
__device__ __forceinline__ u64 pack2(float lo,float hi){
  return (u64)__float_as_uint(lo) | ((u64)__float_as_uint(hi)<<32);
}

__global__ __launch_bounds__(256) void smn_init(float* __restrict__ ws,
                                                float* __restrict__ out,
                                                const float* __restrict__ W_ro,
                                                const float* __restrict__ W_ao){
  unsigned i = blockIdx.x*256u + threadIdx.x, st = gridDim.x*256u;
  u64* stp=(u64*)(ws+OFF_ST); float* cp=ws+OFF_C; u64* mp=(u64*)(ws+OFF_MU);
  for (unsigned k=i;k<131072u;k+=st) st64s(&stp[k],SENT_STATE);
  for (unsigned k=i;k<67584u;k+=st)  st32f(&cp[k],__uint_as_float(SENT_C));
  for (unsigned k=i;k<32768u;k+=st)  st64s(&mp[k],SENT_MU_PAIR);
  for (unsigned k=i;k<10240u;k+=st)  out[k]=0.f;
  // fp16 conversion, slice-major layout: hw[jsl][k][cl]
  __half* hro = (__half*)(ws + OFF_H);
  __half* hao = hro + 65536;
  for (unsigned idx=i; idx<65536u; idx+=st) {
    unsigned k = idx >> 8, c = idx & 255u;
    unsigned dst = (c>>6)*16384u + k*64u + (c&63u);
    hro[dst] = __float2half(W_ro[idx]);
    hao[dst] = __float2half(W_ao[idx]);
  }
}

__global__ __launch_bounds__(512) void smn_main(
    const float* __restrict__ x_in, const float* __restrict__ W_sr,
    const float* __restrict__ W_ma, const float* __restrict__ W_ro,
    const float* __restrict__ W_ao, const float* __restrict__ W_ar,
    const float* __restrict__ W_ra, const float* __restrict__ W_a,
    const float* __restrict__ W_y,  const float* __restrict__ gvec,
    const float* __restrict__ bvec, float* __restrict__ out,
    float* __restrict__ ws)
{
  __shared__ __align__(16) float aF[2][HH], rF[2][HH];   // full state(t)
  __shared__ __align__(16) float P[2][32][2][64];        // k-split matvec partials
  __shared__ __align__(16) float r_hist[33][2][64];
  __shared__ __align__(16) float o_hist[33][2][64];
  __shared__ __align__(8)  __half Wro_l[256][68];        // fp16 LDS-resident B weights
  __shared__ __align__(8)  __half Wao_l[256][68];        // (pad 68 halves -> 8B-aligned rows)
  __shared__ float opre[2][64];
  __shared__ float c_l[33][2];
  __shared__ float mu_l[64];
  __shared__ float muG[16][32][2];
  __shared__ float lam_pow[64];
  __shared__ float x_l[2][5];

  const int tid = threadIdx.x;
  const int bid = blockIdx.x;
  const int grp = bid >> 2, jsl = bid & 3;
  const int b0 = grp * 2, c0 = jsl * 64;
  const int q = tid & 15, ks = tid >> 4;       // matvec map: col quad, k-slice of 8

  u64*   st64    = (u64*)(ws + OFF_ST);
  float* c_parts = ws + OFF_C;
  u64*   mu64    = (u64*)(ws + OFF_MU);

  // per-thread column constants (combine map tid<128 -> b=tid>>6, c=tid&63)
  const int cc2 = c0 + (tid & 63);
  const float gv  = gvec[cc2], bv = bvec[cc2];
  const float wma0=W_ma[cc2], wma1=W_ma[HH+cc2], wma2=W_ma[2*HH+cc2];
  const float wsr0=W_sr[cc2], wsr1=W_sr[HH+cc2];
  if (tid < 64) lam_pow[tid] = powf(0.95f,(float)tid);
  if (tid < 10) x_l[tid/5][tid%5] = x_in[(b0 + tid/5)*5 + tid%5];   // x(0)
  // one-time LDS fill of fp16 B weights (this block's 64-col slice)
  {
    const __half* hro = (const __half*)(ws + OFF_H) + jsl*16384;
    const __half* hao = (const __half*)(ws + OFF_H) + 65536 + jsl*16384;
    for (int i = tid; i < 4096; i += 512) {          // uint2 = 4 halves per chunk
      int k = i >> 4, c4 = (i & 15) * 4;
      *(uint2*)&Wro_l[k][c4] = *(const uint2*)&hro[k*64 + c4];
      *(uint2*)&Wao_l[k][c4] = *(const uint2*)&hao[k*64 + c4];
    }
  }
  __syncthreads();

  for (int t = 0; t <= NSTEPS; ++t) {
    // ================= A: state(t) own slice =================
    if (t < NSTEPS) {
      if (t == 0) {
        if (tid < 128) {
          int b = tid>>6, c = tid&63;
          float va = fmaxf(x_l[b][2]*wma0 + x_l[b][3]*wma1 + x_l[b][4]*wma2, 0.f);
          float vr = fmaxf(x_l[b][0]*wsr0 + x_l[b][1]*wsr1, 0.f);
          aF[b][c0+c]=va; rF[b][c0+c]=vr; r_hist[0][b][c]=vr;
          st64s(&st64[(unsigned)((b0+b)*HH + cc2)], pack2(va,vr));
        }
        __syncthreads();
      } else {
        const int kb = ks*8;
        float sa0[8],sa1[8],sr0[8],sr1[8];
        *(float4*)&sa0[0]=*(const float4*)&aF[0][kb]; *(float4*)&sa0[4]=*(const float4*)&aF[0][kb+4];
        *(float4*)&sa1[0]=*(const float4*)&aF[1][kb]; *(float4*)&sa1[4]=*(const float4*)&aF[1][kb+4];
        *(float4*)&sr0[0]=*(const float4*)&rF[0][kb]; *(float4*)&sr0[4]=*(const float4*)&rF[0][kb+4];
        *(float4*)&sr1[0]=*(const float4*)&rF[1][kb]; *(float4*)&sr1[4]=*(const float4*)&rF[1][kb+4];
        float aA[2][4]={{0.f,0.f,0.f,0.f},{0.f,0.f,0.f,0.f}};
        float aR[2][4]={{0.f,0.f,0.f,0.f},{0.f,0.f,0.f,0.f}};
        #pragma unroll
        for (int kk=0; kk<8; ++kk) {
          const int k = kb + kk;
          const float4 wa = *(const float4*)&W_a [k*HH + c0 + q*4];
          const float4 wr = *(const float4*)&W_ra[k*HH + c0 + q*4];
          const float4 wn = *(const float4*)&W_ar[k*HH + c0 + q*4];
          #pragma unroll
          for (int jj=0;jj<4;++jj){
            const float waj=(&wa.x)[jj], wrj=(&wr.x)[jj], wnj=(&wn.x)[jj];
            aA[0][jj] += sa0[kk]*waj + sr0[kk]*wrj;
            aA[1][jj] += sa1[kk]*waj + sr1[kk]*wrj;
            aR[0][jj] += sa0[kk]*wnj;
            aR[1][jj] += sa1[kk]*wnj;
          }
        }
        *(float4*)&P[0][ks][0][q*4] = make_float4(aA[0][0],aA[0][1],aA[0][2],aA[0][3]);
        *(float4*)&P[0][ks][1][q*4] = make_float4(aA[1][0],aA[1][1],aA[1][2],aA[1][3]);
        *(float4*)&P[1][ks][0][q*4] = make_float4(aR[0][0],aR[0][1],aR[0][2],aR[0][3]);
        *(float4*)&P[1][ks][1][q*4] = make_float4(aR[1][0],aR[1][1],aR[1][2],aR[1][3]);
        __syncthreads();
        if (tid < 128) {
          int b=tid>>6, c=tid&63;
          float sa=0.f, sr=0.f;
          #pragma unroll
          for (int e=0;e<32;++e){ sa+=P[0][e][b][c]; sr+=P[1][e][b][c]; }
          float va = fmaxf(sa + x_l[b][2]*wma0 + x_l[b][3]*wma1 + x_l[b][4]*wma2, 0.f);
          float vr = fmaxf(sr + x_l[b][0]*wsr0 + x_l[b][1]*wsr1, 0.f);
          if (t<=32) r_hist[t][b][c]=vr;
          st64s(&st64[(unsigned)((t&3)*32768) + (unsigned)((b0+b)*HH + cc2)], pack2(va,vr));
          aF[b][c0+c]=va; rF[b][c0+c]=vr;   // own slice of state(t)
        }
        __syncthreads();
      }
      if (t+1 < NSTEPS && tid < 10)
        x_l[tid/5][tid%5] = x_in[((t+1)*128 + b0 + tid/5)*5 + tid%5];
    }

    // ================= fin: finish o(t-1) (late mu poll) =================
    const int tp = t - 1;
    const bool fin = (t >= 1) && (tp <= 32 || tp >= 56);
    if (fin) {
      const int m = (tp <= 32) ? tp : tp - 23;
      {
        const int p = tid & 31, ch = tid >> 5;
        const u64* base = &mu64[(unsigned)(((m&3)*4 + jsl)*64)*32u];
        u64 vals[4]; unsigned rm = 0;
        const u64* ptrs[4];
        #pragma unroll
        for (int gg=0; gg<4; ++gg) ptrs[gg] = &base[(unsigned)((ch*4+gg)*32 + p)];
        while (rm != 0xFu) {
          #pragma unroll
          for (int gg=0; gg<4; ++gg) if (!(rm & (1u<<gg))) {
            u64 v = ld64(ptrs[gg]);
            if ((unsigned)v != SENT_MU && (unsigned)(v>>32) != SENT_MU) { vals[gg]=v; rm |= 1u<<gg; }
          }
        }
        float s0=0.f, s1=0.f;
        #pragma unroll
        for (int gg=0; gg<4; ++gg) { s0 += __uint_as_float((unsigned)vals[gg]);
                                     s1 += __uint_as_float((unsigned)(vals[gg]>>32)); }
        muG[ch][p][0]=s0; muG[ch][p][1]=s1;
      }
      __syncthreads();
      if (tid < 32) {   // reduce + re-sentinel slot (m+3)%4 (occupant m-1: consumed by all)
        float s0=0.f,s1=0.f;
        #pragma unroll
        for (int ch2=0;ch2<16;++ch2){ s0+=muG[ch2][tid][0]; s1+=muG[ch2][tid][1]; }
        mu_l[2*tid]=s0*(1.f/128.f); mu_l[2*tid+1]=s1*(1.f/128.f);
        st64s(&mu64[(unsigned)((((m+3)&3)*4 + jsl)*64 + grp)*32u + (unsigned)tid], SENT_MU_PAIR);
      }
      __syncthreads();
      if (tid < 128) {
        int b=tid>>6, c=tid&63;
        float o = fmaxf(gv*(opre[b][c]-mu_l[c]) + bv, 0.f);
        opre[b][c]=o;
        if (tp<=32) o_hist[tp][b][c]=o;
      }
      __syncthreads();
      if (tp >= 56 && tid < 320) {
        int ow=tid>>4, l16=tid&15, b=ow/10, n=ow%10;
        float acc=0.f;
        #pragma unroll
        for (int i2=0;i2<4;++i2){ int c=l16*4+i2; acc += opre[b][c]*W_y[(c0+c)*10+n]; }
        acc+=__shfl_xor(acc,1); acc+=__shfl_xor(acc,2);
        acc+=__shfl_xor(acc,4); acc+=__shfl_xor(acc,8);
        if (l16==0) atomicAdd(&out[(tp-56)*1280 + (b0+b)*10 + n], acc);
      }
    }
    if (t == NSTEPS) break;

    const bool live = (t <= 32 || t >= 56);
    const int mc = (t <= 32) ? t : t - 23;
    const int smax = (t-1 < 32) ? (t-1) : 32;

    // ======== dots publish (tid<128, live) || state(t) gather (tid>=128) ========
    if (tid < 128) {
      if (live && smax >= 0) {
        const int l8 = tid & 7;
        for (int pp = tid>>3; pp < (smax+1)*2; pp += 16) {
          const int s = pp>>1, b2 = pp&1;
          float acc=0.f;
          #pragma unroll
          for (int i2=0;i2<8;++i2){ int c=l8*8+i2; acc += rF[b2][c0+c]*o_hist[s][b2][c]; }
          acc+=__shfl_xor(acc,1); acc+=__shfl_xor(acc,2); acc+=__shfl_xor(acc,4);
          if (l8==0) st32f(&c_parts[(unsigned)((((mc&3)*33+s)*128 + b0+b2)*4 + jsl)], acc);
        }
      }
    } else {
      const int w = tid - 128;                 // 384 threads: 3 peers x 128 words
      const int pi = w >> 7, w2 = w & 127, b = w2>>6, c64 = w2&63;
      const int jp = (jsl + 1 + pi) & 3;
      const u64* ptr = &st64[(unsigned)((t&3)*32768) + (unsigned)((b0+b)*HH + jp*64 + c64)];
      u64 v;
      for (;;){ v = ld64(ptr); if (v != SENT_STATE) break; }
      aF[b][jp*64+c64] = __uint_as_float((unsigned)v);
      rF[b][jp*64+c64] = __uint_as_float((unsigned)(v>>32));
    }
    __syncthreads();
    // state re-sentinel slot (t+3)%4 (occupant t-1; peers' gather(t-1) proven done)
    if (tid < 128) {
      int b=tid>>6;
      st64s(&st64[(unsigned)(((t+3)&3)*32768) + (unsigned)((b0+b)*HH + cc2)], SENT_STATE);
    }

    // ================= B: o_pre (fp16 LDS weights) + apply + mu publish =================
    if (live) {
      const int kb = ks*8;
      float sa0[8],sa1[8],sr0[8],sr1[8];
      *(float4*)&sa0[0]=*(const float4*)&aF[0][kb]; *(float4*)&sa0[4]=*(const float4*)&aF[0][kb+4];
      *(float4*)&sa1[0]=*(const float4*)&aF[1][kb]; *(float4*)&sa1[4]=*(const float4*)&aF[1][kb+4];
      *(float4*)&sr0[0]=*(const float4*)&rF[0][kb]; *(float4*)&sr0[4]=*(const float4*)&rF[0][kb+4];
      *(float4*)&sr1[0]=*(const float4*)&rF[1][kb]; *(float4*)&sr1[4]=*(const float4*)&rF[1][kb+4];
      float aO[2][4]={{0.f,0.f,0.f,0.f},{0.f,0.f,0.f,0.f}};
      #pragma unroll
      for (int kk=0;kk<8;++kk){
        const int k=kb+kk;
        const __half2* ro2 = (const __half2*)&Wro_l[k][q*4];
        const __half2* ao2 = (const __half2*)&Wao_l[k][q*4];
        const float2 wo01 = __half22float2(ro2[0]), wo23 = __half22float2(ro2[1]);
        const float2 wq01 = __half22float2(ao2[0]), wq23 = __half22float2(ao2[1]);
        const float wof[4] = {wo01.x, wo01.y, wo23.x, wo23.y};
        const float wqf[4] = {wq01.x, wq01.y, wq23.x, wq23.y};
        #pragma unroll
        for (int jj=0;jj<4;++jj){
          aO[0][jj] += sr0[kk]*wof[jj] + sa0[kk]*wqf[jj];
          aO[1][jj] += sr1[kk]*wof[jj] + sa1[kk]*wqf[jj];
        }
      }
      *(float4*)&P[0][ks][0][q*4] = make_float4(aO[0][0],aO[0][1],aO[0][2],aO[0][3]);
      *(float4*)&P[0][ks][1][q*4] = make_float4(aO[1][0],aO[1][1],aO[1][2],aO[1][3]);
      // c gather: 4 parts per (s,b), shfl-sum
      if (smax >= 0 && tid < (smax+1)*8) {
        const int s=tid>>3, b2=(tid>>2)&1, jj2=tid&3;
        const float* ptr=&c_parts[(unsigned)((((mc&3)*33+s)*128 + b0+b2)*4 + jj2)];
        float v;
        for(;;){ v=ld32f(ptr); if (__float_as_uint(v)!=SENT_C) break; }
        v+=__shfl_xor(v,1); v+=__shfl_xor(v,2);
        if (jj2==0) c_l[s][b2]=v;
      }
      __syncthreads();
      // c re-sentinel slot (mc+3)%4 (occupant mc-1: consumed by all group peers)
      if (smax >= 0 && tid >= 128 && tid < 194) {
        const int s=(tid-128)>>1, b2=(tid-128)&1;
        st32f(&c_parts[(unsigned)(((((mc+3)&3)*33+s)*128 + b0+b2)*4 + jsl)],
              __uint_as_float(SENT_C));
      }
      if (tid < 128) {
        int b=tid>>6, c=tid&63;
        float s=0.f;
        #pragma unroll
        for (int e=0;e<32;++e) s+=P[0][e][b][c];
        for (int s2=0;s2<=smax;++s2)
          s += lam_pow[t-1-s2]*0.5f*c_l[s2][b]*r_hist[s2][b][c];
        opre[b][c]=s;
      }
      __syncthreads();
      if (tid < 32) {
        float plo=opre[0][2*tid]+opre[1][2*tid];
        float phi=opre[0][2*tid+1]+opre[1][2*tid+1];
        st64s(&mu64[(unsigned)(((mc&3)*4 + jsl)*64 + grp)*32u + (unsigned)tid], pack2(plo,phi));
      }
    }
  }
}

extern "C" void kernel_launch(void* const* d_in, const int* in_sizes, int n_in,
                              void* d_out, int out_size, void* d_ws, size_t ws_size,
                              hipStream_t stream) {
  if (ws_size < (size_t)WS_FLOATS * 4) return;   // ~1.84 MB scratch
  const float* x_in = (const float*)d_in[0];
  const float* W_sr = (const float*)d_in[1];
  const float* W_ma = (const float*)d_in[2];
  const float* W_ro = (const float*)d_in[3];
  const float* W_ao = (const float*)d_in[4];
  const float* W_ar = (const float*)d_in[5];
  const float* W_ra = (const float*)d_in[6];
  const float* W_a  = (const float*)d_in[7];
  const float* W_y  = (const float*)d_in[8];
  const float* g    = (const float*)d_in[9];
  const float* b    = (const float*)d_in[10];
  float* out = (float*)d_out;
  float* ws  = (float*)d_ws;

  hipLaunchKernelGGL(smn_init, dim3(256), dim3(256), 0, stream, ws, out, W_ro, W_ao);
  hipLaunchKernelGGL(smn_main, dim3(256), dim3(512), 0, stream,
                     x_in, W_sr, W_ma, W_ro, W_ao, W_ar, W_ra, W_a, W_y, g, b,
                     out, ws);
}